// Round 8
// baseline (155.609 us; speedup 1.0000x reference)
//
#include <hip/hip_runtime.h>
#include <math.h>

#define D 196
#define NCH 64
#define NH 8
#define DHD 64
#define INNER 512
#define MLP 784
#define SEQ 65

// static device workspace (fully rewritten every iteration)
__device__ float g_a[NCH * D];        // conv output
__device__ float g_b1[NCH];           // channel means
__device__ float g_qkv[SEQ * 1536];   // qkv
__device__ float g_x2[SEQ * D];       // post-attn residual (atomic-assembled)
__device__ unsigned int g_cnt[SEQ];   // per-row producer counters (k2 -> k3)

__device__ __forceinline__ float bsum(float v, float* red) {   // 256-thread blocks
    for (int off = 32; off > 0; off >>= 1) v += __shfl_down(v, off, 64);
    int lane = threadIdx.x & 63, wid = threadIdx.x >> 6;
    if (lane == 0) red[wid] = v;
    __syncthreads();
    float s = red[0] + red[1] + red[2] + red[3];
    __syncthreads();
    return s;
}

// ===== K1: conv+mean+zero(out,g_x2,g_cnt) (blocks 0..63) | LN1+QKV (64..843) =====
__global__ void __launch_bounds__(256) k1(const float* __restrict__ x_pe,
        const float* __restrict__ conv_k, const float* __restrict__ bn_g,
        const float* __restrict__ bn_b, const float* __restrict__ bn_rm,
        const float* __restrict__ bn_rv, const float* __restrict__ x,
        const float* __restrict__ ln1_g, const float* __restrict__ ln1_b,
        const float* __restrict__ w_qkv, float* __restrict__ out) {
    __shared__ float red[4];
    __shared__ float h[D];
    __shared__ float ps[512];
    int b = blockIdx.x, t = threadIdx.x;
    if (b < NCH) {
        int zi = b * 200 + t;
        if (t < 200 && zi < SEQ * D) { out[zi] = 0.f; g_x2[zi] = 0.f; }
        if (b == 0 && t < SEQ) g_cnt[t] = 0u;
        const float* row = x_pe + b * D;
        float val = 0.f;
        if (t < D) {
            float km0 = conv_k[3], km1 = conv_k[4], km2 = conv_k[5];
            float inv = rsqrtf(bn_rv[0] + 1e-5f);
            float l = (t > 0) ? row[t - 1] : 0.f;
            float m = row[t];
            float r = (t < D - 1) ? row[t + 1] : 0.f;
            float conv = km0 * l + km1 * m + km2 * r;
            float bn = (conv - bn_rm[0]) * inv * bn_g[0] + bn_b[0];
            val = fmaxf(bn, 0.f);
            g_a[b * D + t] = val;
        }
        float tot = bsum(val, red);
        if (t == 0) g_b1[b] = tot * (1.f / (float)D);
    } else {
        int qb = b - NCH;          // 0..779
        int n = qb / 12, cg = qb % 12;
        const float* row = x + n * D;
        float v = (t < D) ? row[t] : 0.f;
        float mean = bsum(v, red) * (1.f / (float)D);
        float d = (t < D) ? (v - mean) : 0.f;
        float var = bsum(d * d, red) * (1.f / (float)D);
        float rinv = rsqrtf(var + 1e-5f);
        if (t < D) h[t] = d * rinv * ln1_g[t] + ln1_b[t];
        __syncthreads();
        int qq = t >> 6, lt = t & 63;        // qq: K quarter, lt: col pair
        int c0 = cg * 128 + lt * 2;
        const float* wp = w_qkv + (qq * 49) * 1536 + c0;
        const float* hp = h + qq * 49;
        float a0 = 0.f, a1 = 0.f;
#pragma unroll
        for (int i = 0; i < 49; i++) {
            float2 w2 = *(const float2*)(wp + i * 1536);
            float hv = hp[i];
            a0 += hv * w2.x;
            a1 += hv * w2.y;
        }
        ps[qq * 128 + lt * 2] = a0;
        ps[qq * 128 + lt * 2 + 1] = a1;
        __syncthreads();
        if (t < 64) {
            float s0 = ps[t * 2] + ps[128 + t * 2] + ps[256 + t * 2] + ps[384 + t * 2];
            float s1 = ps[t * 2 + 1] + ps[129 + t * 2] + ps[257 + t * 2] + ps[385 + t * 2];
            float2 o2 = make_float2(s0, s1);
            *(float2*)(g_qkv + n * 1536 + cg * 128 + t * 2) = o2;
        }
    }
}

// ===== K23: merged k2 (blocks 0..259) + k3 (blocks 260..1299).
//       k3-role blocks wait on per-row counters; 6 blocks/CU guaranteed
//       by launch_bounds -> all 1300 blocks co-resident (1536 slots). =====
__global__ void __launch_bounds__(256, 6) k23(const float* __restrict__ fc_w1,
        const float* __restrict__ fc_w2, const float* __restrict__ w_out,
        const float* __restrict__ b_out, const float* __restrict__ x,
        const float* __restrict__ tokens, const float* __restrict__ ln2_g,
        const float* __restrict__ ln2_b, const float* __restrict__ ff_w1,
        const float* __restrict__ ff_b1, const float* __restrict__ ff_w2,
        const float* __restrict__ ff_b2, float* __restrict__ out) {
    // k2-role shared
    __shared__ float sq[128];
    __shared__ float pp[2 * 80];
    __shared__ float so[128];
    __shared__ float ps[784];
    __shared__ float sb1[NCH];
    __shared__ float sb2[NCH];
    __shared__ float hid[12];
    __shared__ float cgate;
    // k3-role shared
    __shared__ float red[4];
    __shared__ float x2s[D];
    __shared__ float h2s[D];
    __shared__ float st[49];
    __shared__ float psC[196];

    int b = blockIdx.x, t = threadIdx.x;

    if (b < 260) {
        // ---------------- k2 role: attention + out-proj partial ----------------
        int n = b >> 2, g = b & 3;
        int w = t >> 6, L = t & 63;

        if (t < 128) sq[t] = g_qkv[n * 1536 + g * 128 + t];

        if (g == 0) {
            if (t < NCH) {
                sb1[t] = g_b1[t];
                float v = g_b1[t];
                float mx = -1e30f, mn = 1e30f;
                int cle = 0, rank = 0;
                for (int j = 0; j < NCH; j++) {
                    float ww = sb1[j];
                    mx = fmaxf(mx, ww);
                    mn = fminf(mn, ww);
                    if (ww <= 0.f) cle++;
                    if (ww < v || (ww == v && j < t)) rank++;
                }
                int middle;
                if (mx < 0.f || mn > 0.f) middle = 32;
                else if (mx <= 0.f) middle = 0;
                else middle = cle;
                float b2;
                if (rank < middle) {
                    float ls = (float)middle;
                    b2 = v - 1.f / (1.f + powf(ls, v));
                } else {
                    float le = (float)(NCH - middle);
                    b2 = v + 1.f / (1.f + powf(le, -v));
                }
                sb2[t] = b2;
            }
            if (t < 12) {
                float s = 0.f;
                for (int j = 0; j < NCH; j++) s += sb2[j] * fc_w1[j * 12 + t];
                hid[t] = fmaxf(s, 0.f);
            }
            if (t == 0 && n < NCH) {
                float s = 0.f;
                for (int k = 0; k < 12; k++) s += hid[k] * fc_w2[k * NCH + n];
                cgate = 1.f / (1.f + expf(-s));
            }
        }

        if (t < 128) {
            int head = g * 2 + w;
            const float scale = 0.125f;
            const float4* kr = (const float4*)(g_qkv + L * 1536 + INNER + head * DHD);
            const float4* q4 = (const float4*)(sq + w * DHD);
            float s = 0.f;
#pragma unroll
            for (int i = 0; i < 16; i++) {
                float4 kv = kr[i];
                float4 qv = q4[i];
                s += qv.x * kv.x + qv.y * kv.y + qv.z * kv.z + qv.w * kv.w;
            }
            float sL = s * scale;
            float t64 = sq[w * DHD + L] * g_qkv[64 * 1536 + INNER + head * DHD + L];
#pragma unroll
            for (int off = 1; off < 64; off <<= 1) t64 += __shfl_xor(t64, off, 64);
            float s64 = t64 * scale;
            float mx = sL;
#pragma unroll
            for (int off = 1; off < 64; off <<= 1) mx = fmaxf(mx, __shfl_xor(mx, off, 64));
            mx = fmaxf(mx, s64);
            float e = expf(sL - mx);
            float e64 = expf(s64 - mx);
            float esum = e;
#pragma unroll
            for (int off = 1; off < 64; off <<= 1) esum += __shfl_xor(esum, off, 64);
            esum += e64;
            float rs = 1.f / esum;
            pp[w * 80 + L] = e;
            if (L == 0) pp[w * 80 + 64] = e64;
            float acc = 0.f;
#pragma unroll 13
            for (int m = 0; m < SEQ; m++)
                acc += pp[w * 80 + m] * g_qkv[m * 1536 + 2 * INNER + head * DHD + L];
            so[w * DHD + L] = acc * rs;
        }
        __syncthreads();

        if (t < 196) {
            int qq = t / 49, p = t - qq * 49;
            const float* wp = w_out + (g * 128 + qq * 32) * D + 4 * p;
            const float* op = so + qq * 32;
            float a0 = 0.f, a1 = 0.f, a2 = 0.f, a3 = 0.f;
#pragma unroll
            for (int i = 0; i < 32; i++) {
                float4 w4 = *(const float4*)(wp + i * D);
                float ov = op[i];
                a0 += ov * w4.x;
                a1 += ov * w4.y;
                a2 += ov * w4.z;
                a3 += ov * w4.w;
            }
            ps[qq * 196 + 4 * p]     = a0;
            ps[qq * 196 + 4 * p + 1] = a1;
            ps[qq * 196 + 4 * p + 2] = a2;
            ps[qq * 196 + 4 * p + 3] = a3;
        }
        __syncthreads();
        if (t < 196) {
            float sacc = ps[t] + ps[196 + t] + ps[392 + t] + ps[588 + t];
            if (g == 0) {
                float att = (n < NCH) ? g_a[n * D + t] * cgate : tokens[t];
                sacc += x[n * D + t] + b_out[t] + att;
            }
            atomicAdd(&g_x2[n * D + t], sacc);
        }
        // release: make x2 atomics visible, then count this producer
        __threadfence();
        __syncthreads();
        if (t == 0)
            __hip_atomic_fetch_add(&g_cnt[n], 1u, __ATOMIC_RELEASE,
                                   __HIP_MEMORY_SCOPE_AGENT);
    } else {
        // ---------------- k3 role: LN2 + FF1+GELU+FF2 ----------------
        int u = b - 260;
        int n = u >> 4, fg = u & 15;      // fg 0..15
        // wait for the 4 producers of row n (relaxed spin + one acquire)
        if (t == 0) {
            while (__hip_atomic_load(&g_cnt[n], __ATOMIC_RELAXED,
                                     __HIP_MEMORY_SCOPE_AGENT) < 4u)
                __builtin_amdgcn_s_sleep(8);
            (void)__hip_atomic_load(&g_cnt[n], __ATOMIC_ACQUIRE,
                                    __HIP_MEMORY_SCOPE_AGENT);
        }
        __syncthreads();

        float v = 0.f;
        if (t < D) { v = g_x2[n * D + t]; x2s[t] = v; }
        float mean = bsum(v, red) * (1.f / (float)D);
        float d = (t < D) ? (v - mean) : 0.f;
        float var = bsum(d * d, red) * (1.f / (float)D);
        float rinv = rsqrtf(var + 1e-5f);
        if (t < D) h2s[t] = d * rinv * ln2_g[t] + ln2_b[t];
        __syncthreads();
        // FF1 splitK4 over this unit's 49 columns
        if (t < 196) {
            int qq = t / 49, p = t - qq * 49;    // K quarter, column
            int c0 = fg * 49 + p;
            const float* wp = ff_w1 + (qq * 49) * MLP + c0;
            const float* hp = h2s + qq * 49;
            float a0 = 0.f;
#pragma unroll
            for (int i = 0; i < 49; i++) a0 += hp[i] * wp[i * MLP];
            psC[qq * 49 + p] = a0;
        }
        __syncthreads();
        if (t < 49) {
            float s0 = psC[t] + psC[49 + t] + psC[98 + t] + psC[147 + t] + ff_b1[fg * 49 + t];
            st[t] = 0.5f * s0 * (1.f + erff(s0 * 0.70710678118f));
        }
        __syncthreads();
        // FF2: each thread owns one output column over this unit's 49 K rows
        if (t < D) {
            const float* wp = ff_w2 + (fg * 49) * D + t;
            float s = 0.f;
#pragma unroll
            for (int i = 0; i < 49; i++) s += st[i] * wp[i * D];
            if (fg == 0) s += ff_b2[t] + x2s[t];
            atomicAdd(&out[n * D + t], s);
        }
    }
}

extern "C" void kernel_launch(void* const* d_in, const int* in_sizes, int n_in,
                              void* d_out, int out_size, void* d_ws, size_t ws_size,
                              hipStream_t stream) {
    const float* x      = (const float*)d_in[0];
    const float* tokens = (const float*)d_in[1];
    const float* x_pe   = (const float*)d_in[2];
    const float* conv_k = (const float*)d_in[3];
    const float* bn_g   = (const float*)d_in[4];
    const float* bn_b   = (const float*)d_in[5];
    const float* bn_rm  = (const float*)d_in[6];
    const float* bn_rv  = (const float*)d_in[7];
    const float* fc_w1  = (const float*)d_in[8];
    const float* fc_w2  = (const float*)d_in[9];
    const float* ln1_g  = (const float*)d_in[10];
    const float* ln1_b  = (const float*)d_in[11];
    const float* ln2_g  = (const float*)d_in[12];
    const float* ln2_b  = (const float*)d_in[13];
    const float* w_qkv  = (const float*)d_in[14];
    const float* w_out  = (const float*)d_in[15];
    const float* b_out  = (const float*)d_in[16];
    const float* ff_w1  = (const float*)d_in[17];
    const float* ff_b1  = (const float*)d_in[18];
    const float* ff_w2  = (const float*)d_in[19];
    const float* ff_b2  = (const float*)d_in[20];
    float* out = (float*)d_out;
    (void)d_ws; (void)ws_size;   // workspace unused: scratch lives in __device__ globals

    k1<<<844, 256, 0, stream>>>(x_pe, conv_k, bn_g, bn_b, bn_rm, bn_rv,
                                x, ln1_g, ln1_b, w_qkv, out);
    k23<<<260 + SEQ * 16, 256, 0, stream>>>(fc_w1, fc_w2, w_out, b_out, x, tokens,
                                            ln2_g, ln2_b, ff_w1, ff_b1,
                                            ff_w2, ff_b2, out);
}

// Round 9
// 122.100 us; speedup vs baseline: 1.2744x; 1.2744x over previous
//
#include <hip/hip_runtime.h>
#include <math.h>

#define D 196
#define NCH 64
#define NH 8
#define DHD 64
#define INNER 512
#define MLP 784
#define SEQ 65

// static device workspace (fully rewritten every iteration)
__device__ float g_a[NCH * D];        // conv output
__device__ float g_b1[NCH];           // channel means
__device__ float g_qkv[SEQ * 1536];   // qkv
__device__ float g_x2[SEQ * D];       // post-attn residual (atomic-assembled)

__device__ __forceinline__ float bsum(float v, float* red) {   // 256-thread blocks
    for (int off = 32; off > 0; off >>= 1) v += __shfl_down(v, off, 64);
    int lane = threadIdx.x & 63, wid = threadIdx.x >> 6;
    if (lane == 0) red[wid] = v;
    __syncthreads();
    float s = red[0] + red[1] + red[2] + red[3];
    __syncthreads();
    return s;
}

// one-pass (sum, sumsq) block reduction: 2 barriers instead of 4
__device__ __forceinline__ float2 bsum2(float a, float b, float2* red) {
    for (int off = 32; off > 0; off >>= 1) {
        a += __shfl_down(a, off, 64);
        b += __shfl_down(b, off, 64);
    }
    int lane = threadIdx.x & 63, wid = threadIdx.x >> 6;
    if (lane == 0) red[wid] = make_float2(a, b);
    __syncthreads();
    float2 s = make_float2(red[0].x + red[1].x + red[2].x + red[3].x,
                           red[0].y + red[1].y + red[2].y + red[3].y);
    __syncthreads();
    return s;
}

// ===== K1: conv+mean+zero (blocks 0..63) | LN1+QKV float4, 256-col groups
//       (blocks 64..453: qb=b-64, n=qb/6, cg=qb%6) =====
__global__ void __launch_bounds__(256) k1(const float* __restrict__ x_pe,
        const float* __restrict__ conv_k, const float* __restrict__ bn_g,
        const float* __restrict__ bn_b, const float* __restrict__ bn_rm,
        const float* __restrict__ bn_rv, const float* __restrict__ x,
        const float* __restrict__ ln1_g, const float* __restrict__ ln1_b,
        const float* __restrict__ w_qkv, float* __restrict__ out) {
    __shared__ float red[4];
    __shared__ float2 red2[4];
    __shared__ float h[D];
    __shared__ float ps[1024];
    int b = blockIdx.x, t = threadIdx.x;
    if (b < NCH) {
        int zi = b * 200 + t;
        if (t < 200 && zi < SEQ * D) { out[zi] = 0.f; g_x2[zi] = 0.f; }
        const float* row = x_pe + b * D;
        float val = 0.f;
        if (t < D) {
            float km0 = conv_k[3], km1 = conv_k[4], km2 = conv_k[5];
            float inv = rsqrtf(bn_rv[0] + 1e-5f);
            float l = (t > 0) ? row[t - 1] : 0.f;
            float m = row[t];
            float r = (t < D - 1) ? row[t + 1] : 0.f;
            float conv = km0 * l + km1 * m + km2 * r;
            float bn = (conv - bn_rm[0]) * inv * bn_g[0] + bn_b[0];
            val = fmaxf(bn, 0.f);
            g_a[b * D + t] = val;
        }
        float tot = bsum(val, red);
        if (t == 0) g_b1[b] = tot * (1.f / (float)D);
    } else {
        int qb = b - NCH;          // 0..389
        int n = qb / 6, cg = qb % 6;
        const float* row = x + n * D;
        float v = (t < D) ? row[t] : 0.f;
        float2 ss = bsum2(v, v * v, red2);
        float mean = ss.x * (1.f / (float)D);
        float var = ss.y * (1.f / (float)D) - mean * mean;
        float rinv = rsqrtf(var + 1e-5f);
        if (t < D) h[t] = (v - mean) * rinv * ln1_g[t] + ln1_b[t];
        __syncthreads();
        int qq = t >> 6, lane = t & 63;      // K quarter, col quad
        int c0 = cg * 256 + lane * 4;
        const float* wp = w_qkv + (qq * 49) * 1536 + c0;
        const float* hp = h + qq * 49;
        float a0 = 0.f, a1 = 0.f, a2 = 0.f, a3 = 0.f;
#pragma unroll
        for (int i = 0; i < 49; i++) {
            float4 w4 = *(const float4*)(wp + i * 1536);
            float hv = hp[i];
            a0 += hv * w4.x;
            a1 += hv * w4.y;
            a2 += hv * w4.z;
            a3 += hv * w4.w;
        }
        ps[qq * 256 + lane * 4]     = a0;
        ps[qq * 256 + lane * 4 + 1] = a1;
        ps[qq * 256 + lane * 4 + 2] = a2;
        ps[qq * 256 + lane * 4 + 3] = a3;
        __syncthreads();
        if (t < 64) {
            int c = t * 4;
            float4 p0 = *(const float4*)&ps[c];
            float4 p1 = *(const float4*)&ps[256 + c];
            float4 p2 = *(const float4*)&ps[512 + c];
            float4 p3 = *(const float4*)&ps[768 + c];
            float4 o4 = make_float4(p0.x + p1.x + p2.x + p3.x,
                                    p0.y + p1.y + p2.y + p3.y,
                                    p0.z + p1.z + p2.z + p3.z,
                                    p0.w + p1.w + p2.w + p3.w);
            *(float4*)(g_qkv + n * 1536 + cg * 256 + c) = o4;
        }
    }
}

// ===== K2: attention (2 heads) + splitK out-proj partial, grid (65,4) x 256 =====
__global__ void __launch_bounds__(256) k2(const float* __restrict__ fc_w1,
        const float* __restrict__ fc_w2, const float* __restrict__ w_out,
        const float* __restrict__ b_out, const float* __restrict__ x,
        const float* __restrict__ tokens) {
    __shared__ float sq[128];      // q for this block's 2 heads
    __shared__ float pp[2 * 80];   // attn probs per head
    __shared__ float so[128];      // attn out (2 x 64)
    __shared__ float ps[784];      // 4 x 196 splitK partials
    __shared__ float sb1[NCH];
    __shared__ float sb2[NCH];
    __shared__ float hid[12];
    __shared__ float cgate;

    int n = blockIdx.x, g = blockIdx.y, t = threadIdx.x;
    int w = t >> 6, L = t & 63;

    if (t < 128) sq[t] = g_qkv[n * 1536 + g * 128 + t];

    // ---- gate: entirely within wave 0 of g==0 blocks, no barriers ----
    if (g == 0) {
        if (t < NCH) {
            sb1[t] = g_b1[t];
            float v = g_b1[t];
            float mx = -1e30f, mn = 1e30f;
            int cle = 0, rank = 0;
            for (int j = 0; j < NCH; j++) {
                float ww = sb1[j];
                mx = fmaxf(mx, ww);
                mn = fminf(mn, ww);
                if (ww <= 0.f) cle++;
                if (ww < v || (ww == v && j < t)) rank++;
            }
            int middle;
            if (mx < 0.f || mn > 0.f) middle = 32;
            else if (mx <= 0.f) middle = 0;
            else middle = cle;
            float b2;
            if (rank < middle) {
                float ls = (float)middle;
                b2 = v - 1.f / (1.f + powf(ls, v));
            } else {
                float le = (float)(NCH - middle);
                b2 = v + 1.f / (1.f + powf(le, -v));
            }
            sb2[t] = b2;
        }
        if (t < 12) {
            float s = 0.f;
            for (int j = 0; j < NCH; j++) s += sb2[j] * fc_w1[j * 12 + t];
            hid[t] = fmaxf(s, 0.f);
        }
        if (t == 0 && n < NCH) {
            float s = 0.f;
            for (int k = 0; k < 12; k++) s += hid[k] * fc_w2[k * NCH + n];
            cgate = 1.f / (1.f + expf(-s));
        }
    }

    // ---- attention: waves 0,1 = this block's 2 heads (same-wave LDS) ----
    if (t < 128) {
        int head = g * 2 + w;
        const float scale = 0.125f;
        const float4* kr = (const float4*)(g_qkv + L * 1536 + INNER + head * DHD);
        const float4* q4 = (const float4*)(sq + w * DHD);
        float s = 0.f;
#pragma unroll
        for (int i = 0; i < 16; i++) {
            float4 kv = kr[i];
            float4 qv = q4[i];
            s += qv.x * kv.x + qv.y * kv.y + qv.z * kv.z + qv.w * kv.w;
        }
        float sL = s * scale;
        float t64 = sq[w * DHD + L] * g_qkv[64 * 1536 + INNER + head * DHD + L];
#pragma unroll
        for (int off = 1; off < 64; off <<= 1) t64 += __shfl_xor(t64, off, 64);
        float s64 = t64 * scale;
        float mx = sL;
#pragma unroll
        for (int off = 1; off < 64; off <<= 1) mx = fmaxf(mx, __shfl_xor(mx, off, 64));
        mx = fmaxf(mx, s64);
        float e = expf(sL - mx);
        float e64 = expf(s64 - mx);
        float esum = e;
#pragma unroll
        for (int off = 1; off < 64; off <<= 1) esum += __shfl_xor(esum, off, 64);
        esum += e64;
        float rs = 1.f / esum;
        pp[w * 80 + L] = e;
        if (L == 0) pp[w * 80 + 64] = e64;
        float acc = 0.f;
#pragma unroll 13
        for (int m = 0; m < SEQ; m++)
            acc += pp[w * 80 + m] * g_qkv[m * 1536 + 2 * INNER + head * DHD + L];
        so[w * DHD + L] = acc * rs;
    }
    __syncthreads();

    // ---- out-proj partial: K = this block's 128 dims, splitK4 x col-quads ----
    if (t < 196) {
        int qq = t / 49, p = t - qq * 49;
        const float* wp = w_out + (g * 128 + qq * 32) * D + 4 * p;
        const float* op = so + qq * 32;
        float a0 = 0.f, a1 = 0.f, a2 = 0.f, a3 = 0.f;
#pragma unroll
        for (int i = 0; i < 32; i++) {
            float4 w4 = *(const float4*)(wp + i * D);
            float ov = op[i];
            a0 += ov * w4.x;
            a1 += ov * w4.y;
            a2 += ov * w4.z;
            a3 += ov * w4.w;
        }
        ps[qq * 196 + 4 * p]     = a0;
        ps[qq * 196 + 4 * p + 1] = a1;
        ps[qq * 196 + 4 * p + 2] = a2;
        ps[qq * 196 + 4 * p + 3] = a3;
    }
    __syncthreads();
    if (t < 196) {
        float sacc = ps[t] + ps[196 + t] + ps[392 + t] + ps[588 + t];
        if (g == 0) {
            float att = (n < NCH) ? g_a[n * D + t] * cgate : tokens[t];
            sacc += x[n * D + t] + b_out[t] + att;
        }
        atomicAdd(&g_x2[n * D + t], sacc);
    }
}

// ===== K3: LN2 (one-pass, redundant) + FF1(49 cols)+GELU+FF2 column-dots
//       + atomicAdd, grid (65,16) x 256 =====
__global__ void __launch_bounds__(256) k3(const float* __restrict__ ln2_g,
        const float* __restrict__ ln2_b, const float* __restrict__ ff_w1,
        const float* __restrict__ ff_b1, const float* __restrict__ ff_w2,
        const float* __restrict__ ff_b2, float* __restrict__ out) {
    __shared__ float2 red2[4];
    __shared__ float x2s[D];
    __shared__ float h2s[D];
    __shared__ float st[49];
    __shared__ float ps[196];
    int n = blockIdx.x, cg = blockIdx.y, t = threadIdx.x;   // cg 0..15
    float v = 0.f;
    if (t < D) { v = g_x2[n * D + t]; x2s[t] = v; }
    float2 ss = bsum2(v, v * v, red2);
    float mean = ss.x * (1.f / (float)D);
    float var = ss.y * (1.f / (float)D) - mean * mean;
    float rinv = rsqrtf(var + 1e-5f);
    if (t < D) h2s[t] = (v - mean) * rinv * ln2_g[t] + ln2_b[t];
    __syncthreads();
    // FF1 splitK4 over this block's 49 columns
    if (t < 196) {
        int qq = t / 49, p = t - qq * 49;    // K quarter, column
        int c0 = cg * 49 + p;
        const float* wp = ff_w1 + (qq * 49) * MLP + c0;
        const float* hp = h2s + qq * 49;
        float a0 = 0.f;
#pragma unroll
        for (int i = 0; i < 49; i++) a0 += hp[i] * wp[i * MLP];
        ps[qq * 49 + p] = a0;
    }
    __syncthreads();
    if (t < 49) {
        float s0 = ps[t] + ps[49 + t] + ps[98 + t] + ps[147 + t] + ff_b1[cg * 49 + t];
        st[t] = 0.5f * s0 * (1.f + erff(s0 * 0.70710678118f));
    }
    __syncthreads();
    // FF2: each thread owns one output column over this block's 49 K rows
    if (t < D) {
        const float* wp = ff_w2 + (cg * 49) * D + t;
        float s = 0.f;
#pragma unroll
        for (int i = 0; i < 49; i++) s += st[i] * wp[i * D];
        if (cg == 0) s += ff_b2[t] + x2s[t];
        atomicAdd(&out[n * D + t], s);
    }
}

extern "C" void kernel_launch(void* const* d_in, const int* in_sizes, int n_in,
                              void* d_out, int out_size, void* d_ws, size_t ws_size,
                              hipStream_t stream) {
    const float* x      = (const float*)d_in[0];
    const float* tokens = (const float*)d_in[1];
    const float* x_pe   = (const float*)d_in[2];
    const float* conv_k = (const float*)d_in[3];
    const float* bn_g   = (const float*)d_in[4];
    const float* bn_b   = (const float*)d_in[5];
    const float* bn_rm  = (const float*)d_in[6];
    const float* bn_rv  = (const float*)d_in[7];
    const float* fc_w1  = (const float*)d_in[8];
    const float* fc_w2  = (const float*)d_in[9];
    const float* ln1_g  = (const float*)d_in[10];
    const float* ln1_b  = (const float*)d_in[11];
    const float* ln2_g  = (const float*)d_in[12];
    const float* ln2_b  = (const float*)d_in[13];
    const float* w_qkv  = (const float*)d_in[14];
    const float* w_out  = (const float*)d_in[15];
    const float* b_out  = (const float*)d_in[16];
    const float* ff_w1  = (const float*)d_in[17];
    const float* ff_b1  = (const float*)d_in[18];
    const float* ff_w2  = (const float*)d_in[19];
    const float* ff_b2  = (const float*)d_in[20];
    float* out = (float*)d_out;
    (void)d_ws; (void)ws_size;   // workspace unused: scratch lives in __device__ globals

    k1<<<NCH + SEQ * 6, 256, 0, stream>>>(x_pe, conv_k, bn_g, bn_b, bn_rm, bn_rv,
                                          x, ln1_g, ln1_b, w_qkv, out);
    k2<<<dim3(SEQ, 4), 256, 0, stream>>>(fc_w1, fc_w2, w_out, b_out, x, tokens);
    k3<<<dim3(SEQ, 16), 256, 0, stream>>>(ln2_g, ln2_b,
                                          ff_w1, ff_b1, ff_w2, ff_b2, out);
}